// Round 12
// baseline (19.425 us; speedup 1.0000x reference)
//
#include <hip/hip_runtime.h>
#include <math.h>

#define NS 21          // percept rows (index 0 unused, idx in [1,20])
#define NPAIR (NS*NS)  // 441 precomputed pairs

typedef float float4v __attribute__((ext_vector_type(4)));
typedef float float2v __attribute__((ext_vector_type(2)));

#define LOG2E 1.4426950408889634f
#define LN2   0.6931471805599453f

// x >= 0 ; 0^r -> exp2(r * -inf) = 0, correct for r > 0
__device__ __forceinline__ float fast_pow(float x, float r) {
    return __builtin_amdgcn_exp2f(r * __builtin_amdgcn_logf(x));
}

__global__ __launch_bounds__(256) void rank_rt_kernel(
    const int*   __restrict__ idx,      // (nrows, 5)
    const float* __restrict__ percept,  // (21, 3)
    const float* __restrict__ w,        // (3,)
    const float* __restrict__ rho_p,
    const float* __restrict__ beta_p,
    const float* __restrict__ tau_p,
    const float* __restrict__ gamma_p,
    const float* __restrict__ upper_p,
    const float* __restrict__ mid_p,
    const float* __restrict__ rate_p,
    float* __restrict__ out,            // p: nrows*4, then rt: nrows
    int nrows,
    int NT)                             // total threads = ceil(nrows/4)
{
    __shared__ float2v tab[NPAIR];      // {s, s*log(s)} per (q,r)

    // ---- per-block table build: fast-math pow, ~2 entries/thread ----
    {
        const float rho   = rho_p[0];
        const float beta  = beta_p[0];
        const float tau   = tau_p[0];
        const float gamma = gamma_p[0];
        const float w0 = w[0], w1 = w[1], w2 = w[2];
        const float inv_rho = 1.0f / rho;
        for (int e = threadIdx.x; e < NPAIR; e += 256) {
            int q = e / NS;
            int r = e - q * NS;
            float dx = fabsf(percept[q * 3 + 0] - percept[r * 3 + 0]);
            float dy = fabsf(percept[q * 3 + 1] - percept[r * 3 + 1]);
            float dz = fabsf(percept[q * 3 + 2] - percept[r * 3 + 2]);
            float acc = w0 * fast_pow(dx, rho) + w1 * fast_pow(dy, rho)
                      + w2 * fast_pow(dz, rho);
            float d = fast_pow(acc, inv_rho);
            float s = __builtin_amdgcn_exp2f(-beta * LOG2E * fast_pow(d, tau)) + gamma;
            float2v o;
            o.x = s;
            o.y = s * (LN2 * __builtin_amdgcn_logf(s));
            tab[e] = o;
        }
    }
    const float upper = upper_p[0];
    const float mid   = mid_p[0];
    const float rate  = rate_p[0];
    __syncthreads();

    const int t = blockIdx.x * 256 + threadIdx.x;

    // ---- 4 rows per thread, 4-way split-chunk: stores stay lane-contiguous ----
    int rows[4];
    bool has[4];
    int v[4][5];
    #pragma unroll
    for (int c = 0; c < 4; ++c) {
        rows[c] = t + c * NT;
        has[c]  = rows[c] < nrows;
        if (has[c]) {
            const size_t b = (size_t)rows[c] * 5;
            v[c][0] = idx[b];   v[c][1] = idx[b+1]; v[c][2] = idx[b+2];
            v[c][3] = idx[b+3]; v[c][4] = idx[b+4];
        }
    }

    #pragma unroll
    for (int c = 0; c < 4; ++c) {
        if (!has[c]) continue;
        const int row = rows[c];

        const int qb = v[c][0] * NS;
        float2v e0 = tab[qb + v[c][1]];
        float2v e1 = tab[qb + v[c][2]];
        float2v e2 = tab[qb + v[c][3]];
        float2v e3 = tab[qb + v[c][4]];

        float S = (e0.x + e1.x) + (e2.x + e3.x);
        float T = (e0.y + e1.y) + (e2.y + e3.y);
        float invS = __builtin_amdgcn_rcpf(S);

        float ent = LN2 * __builtin_amdgcn_logf(S) - T * invS;   // -sum p log p
        float z   = -rate * (ent - mid);
        float rt  = upper * __builtin_amdgcn_rcpf(
                        1.0f + __builtin_amdgcn_exp2f(z * LOG2E));

        float4v p;
        p.x = e0.x * invS;
        p.y = e1.x * invS;
        p.z = e2.x * invS;
        p.w = e3.x * invS;
        *reinterpret_cast<float4v*>(out + (size_t)row * 4) = p;
        out[(size_t)nrows * 4 + row] = rt;
    }
}

extern "C" void kernel_launch(void* const* d_in, const int* in_sizes, int n_in,
                              void* d_out, int out_size, void* d_ws, size_t ws_size,
                              hipStream_t stream) {
    const int*   idx     = (const int*)  d_in[0];
    const float* percept = (const float*)d_in[1];
    const float* w       = (const float*)d_in[2];
    const float* rho     = (const float*)d_in[3];
    const float* beta    = (const float*)d_in[4];
    const float* tau     = (const float*)d_in[5];
    const float* gamma   = (const float*)d_in[6];
    const float* upper   = (const float*)d_in[7];
    const float* mid     = (const float*)d_in[8];
    const float* rate    = (const float*)d_in[9];
    float* out = (float*)d_out;

    const int nrows = in_sizes[0] / 5;
    const int NT    = (nrows + 3) / 4;      // 4 rows per thread, 4-way split-chunk
    const int block = 256;
    const int grid  = (NT + block - 1) / block;   // 2048 blocks at B=2M: one generation

    rank_rt_kernel<<<grid, block, 0, stream>>>(
        idx, percept, w, rho, beta, tau, gamma, upper, mid, rate, out, nrows, NT);
}

// Round 13
// 19.196 us; speedup vs baseline: 1.0119x; 1.0119x over previous
//
#include <hip/hip_runtime.h>
#include <math.h>

#define NS 21          // percept rows (index 0 unused, idx in [1,20])
#define NPAIR (NS*NS)  // 441 precomputed pairs

typedef float float4v __attribute__((ext_vector_type(4)));
typedef float float2v __attribute__((ext_vector_type(2)));

#define LOG2E 1.4426950408889634f
#define LN2   0.6931471805599453f

// x >= 0 ; 0^r -> exp2(r * -inf) = 0, correct for r > 0
__device__ __forceinline__ float fast_pow(float x, float r) {
    return __builtin_amdgcn_exp2f(r * __builtin_amdgcn_logf(x));
}

__global__ __launch_bounds__(256) void rank_rt_kernel(
    const int*   __restrict__ idx,      // (nrows, 5)
    const float* __restrict__ percept,  // (21, 3)
    const float* __restrict__ w,        // (3,)
    const float* __restrict__ rho_p,
    const float* __restrict__ beta_p,
    const float* __restrict__ tau_p,
    const float* __restrict__ gamma_p,
    const float* __restrict__ upper_p,
    const float* __restrict__ mid_p,
    const float* __restrict__ rate_p,
    float* __restrict__ out,            // p: nrows*4, then rt: nrows
    int nrows,
    int NT)                             // total threads = ceil(nrows/2)
{
    __shared__ float2v tab[NPAIR];      // {s, s*log(s)} per (q,r)

    // ---- per-block table build: fast-math pow, ~2 entries/thread ----
    {
        const float rho   = rho_p[0];
        const float beta  = beta_p[0];
        const float tau   = tau_p[0];
        const float gamma = gamma_p[0];
        const float w0 = w[0], w1 = w[1], w2 = w[2];
        const float inv_rho = 1.0f / rho;
        for (int e = threadIdx.x; e < NPAIR; e += 256) {
            int q = e / NS;
            int r = e - q * NS;
            float dx = fabsf(percept[q * 3 + 0] - percept[r * 3 + 0]);
            float dy = fabsf(percept[q * 3 + 1] - percept[r * 3 + 1]);
            float dz = fabsf(percept[q * 3 + 2] - percept[r * 3 + 2]);
            float acc = w0 * fast_pow(dx, rho) + w1 * fast_pow(dy, rho)
                      + w2 * fast_pow(dz, rho);
            float d = fast_pow(acc, inv_rho);
            float s = __builtin_amdgcn_exp2f(-beta * LOG2E * fast_pow(d, tau)) + gamma;
            float2v o;
            o.x = s;
            o.y = s * (LN2 * __builtin_amdgcn_logf(s));
            tab[e] = o;
        }
    }
    const float upper = upper_p[0];
    const float mid   = mid_p[0];
    const float rate  = rate_p[0];
    __syncthreads();

    const int t = blockIdx.x * 256 + threadIdx.x;
    const int row0 = t;                 // chunk 0: lane-contiguous
    const int row1 = t + NT;            // chunk 1: lane-contiguous
    const bool has0 = row0 < nrows;
    const bool has1 = row1 < nrows;

    // ---- issue both rows' idx loads upfront (10 independent dwords) ----
    int v0[5], v1[5];
    if (has0) {
        const size_t b = (size_t)row0 * 5;
        v0[0] = idx[b]; v0[1] = idx[b+1]; v0[2] = idx[b+2]; v0[3] = idx[b+3]; v0[4] = idx[b+4];
    }
    if (has1) {
        const size_t b = (size_t)row1 * 5;
        v1[0] = idx[b]; v1[1] = idx[b+1]; v1[2] = idx[b+2]; v1[3] = idx[b+3]; v1[4] = idx[b+4];
    }

    #pragma unroll
    for (int c = 0; c < 2; ++c) {
        const bool has = c ? has1 : has0;
        if (!has) continue;
        const int* v = c ? v1 : v0;
        const int row = c ? row1 : row0;

        const int qb = v[0] * NS;
        float2v e0 = tab[qb + v[1]];
        float2v e1 = tab[qb + v[2]];
        float2v e2 = tab[qb + v[3]];
        float2v e3 = tab[qb + v[4]];

        float S = (e0.x + e1.x) + (e2.x + e3.x);
        float T = (e0.y + e1.y) + (e2.y + e3.y);
        float invS = __builtin_amdgcn_rcpf(S);

        float ent = LN2 * __builtin_amdgcn_logf(S) - T * invS;   // -sum p log p
        float z   = -rate * (ent - mid);
        float rt  = upper * __builtin_amdgcn_rcpf(
                        1.0f + __builtin_amdgcn_exp2f(z * LOG2E));

        float4v p;
        p.x = e0.x * invS;
        p.y = e1.x * invS;
        p.z = e2.x * invS;
        p.w = e3.x * invS;
        *reinterpret_cast<float4v*>(out + (size_t)row * 4) = p;
        out[(size_t)nrows * 4 + row] = rt;
    }
}

extern "C" void kernel_launch(void* const* d_in, const int* in_sizes, int n_in,
                              void* d_out, int out_size, void* d_ws, size_t ws_size,
                              hipStream_t stream) {
    const int*   idx     = (const int*)  d_in[0];
    const float* percept = (const float*)d_in[1];
    const float* w       = (const float*)d_in[2];
    const float* rho     = (const float*)d_in[3];
    const float* beta    = (const float*)d_in[4];
    const float* tau     = (const float*)d_in[5];
    const float* gamma   = (const float*)d_in[6];
    const float* upper   = (const float*)d_in[7];
    const float* mid     = (const float*)d_in[8];
    const float* rate    = (const float*)d_in[9];
    float* out = (float*)d_out;

    const int nrows = in_sizes[0] / 5;
    const int NT    = (nrows + 1) / 2;      // 2 rows per thread, split-chunk
    const int block = 256;
    const int grid  = (NT + block - 1) / block;   // 4096 blocks at B=2M

    rank_rt_kernel<<<grid, block, 0, stream>>>(
        idx, percept, w, rho, beta, tau, gamma, upper, mid, rate, out, nrows, NT);
}